// Round 1
// baseline (769.182 us; speedup 1.0000x reference)
//
#include <hip/hip_runtime.h>
#include <stdint.h>

#define BATCH 16
#define HH    320
#define WW    320
#define HW    (HH * WW)          // 102400 = 400 * 256
#define PDIM  64
#define TOPK  100
#define CAPMAX 16384             // per-batch candidate capacity (expect ~11.4k)

// Output layout (all float32, concatenated in reference return order):
#define COORS_OFF   0
#define COORS_SZ    (BATCH * TOPK * 2)        // 3200
#define PARAMS_OFF  (COORS_OFF + COORS_SZ)    // 3200
#define PARAMS_SZ   (BATCH * TOPK * PDIM)     // 102400
#define SCORES_OFF  (PARAMS_OFF + PARAMS_SZ)  // 105600
#define SCORES_SZ   (BATCH * TOPK)            // 1600
#define MASK_OFF    (SCORES_OFF + SCORES_SZ)  // 107200

// ws layout: [0, 64) bytes: int counts[16]; at byte 256: u64 cand[BATCH][cap]

__global__ void peak_kernel(const float* __restrict__ hms,
                            unsigned long long* __restrict__ cand,
                            int* __restrict__ counts, int cap) {
    const int pix = blockIdx.x * blockDim.x + threadIdx.x;   // grid.x*256 == HW exactly
    const int b   = blockIdx.y;
    const int y = pix / WW;
    const int x = pix - y * WW;
    const float* img = hms + (size_t)b * HW;
    const float c = img[pix];
    bool peak = true;
    if (y > 0) {
        const float* r = img + pix - WW;
        if (x > 0)      peak &= (c >= r[-1]);
        peak &= (c >= r[0]);
        if (x < WW - 1) peak &= (c >= r[1]);
    }
    {
        const float* r = img + pix;
        if (x > 0)      peak &= (c >= r[-1]);
        if (x < WW - 1) peak &= (c >= r[1]);
    }
    if (y < HH - 1) {
        const float* r = img + pix + WW;
        if (x > 0)      peak &= (c >= r[-1]);
        peak &= (c >= r[0]);
        if (x < WW - 1) peak &= (c >= r[1]);
    }
    if (peak && c > 0.5f) {
        int slot = atomicAdd(&counts[b], 1);
        if (slot < cap) {
            unsigned int vb = __float_as_uint(c);
            // key: value desc, pixel-index asc on tie
            cand[(size_t)b * cap + slot] =
                ((unsigned long long)vb << 32) | (unsigned int)(~pix);
        }
    }
}

#define NBUCK 256
#define TOPCAP 2048

__global__ __launch_bounds__(256)
void select_kernel(const unsigned long long* __restrict__ cand,
                   const int* __restrict__ counts,
                   const float* __restrict__ pms,
                   float* __restrict__ out, int cap) {
    __shared__ int hist[NBUCK];
    __shared__ int suf[NBUCK + 1];
    __shared__ unsigned long long top[TOPCAP];
    __shared__ int topcount;
    __shared__ int bstar;
    __shared__ int sel_pix[TOPK];

    const int b = blockIdx.x;
    const int tid = threadIdx.x;
    int n = counts[b];
    if (n > cap) n = cap;
    const unsigned long long* cb = cand + (size_t)b * cap;

    if (tid < NBUCK) hist[tid] = 0;
    if (tid == 0) { topcount = 0; bstar = 0; }
    __syncthreads();

    // phase 1: histogram over float-bit buckets (monotonic for positive floats)
    for (int i = tid; i < n; i += 256) {
        unsigned int vb = (unsigned int)(cb[i] >> 32);
        int bk = (int)((vb - 0x3F000000u) >> 15);   // (0.5,1.0) -> [0,255]
        bk = bk < 0 ? 0 : (bk > NBUCK - 1 ? NBUCK - 1 : bk);
        atomicAdd(&hist[bk], 1);
    }
    __syncthreads();

    // phase 2: suffix sums suf[t] = sum_{u>=t} hist[u]
    if (tid < NBUCK) suf[tid] = hist[tid];
    if (tid == 0) suf[NBUCK] = 0;
    __syncthreads();
    for (int d = 1; d < NBUCK; d <<= 1) {
        int v = 0;
        if (tid < NBUCK && tid + d < NBUCK) v = suf[tid + d];
        __syncthreads();
        if (tid < NBUCK) suf[tid] += v;
        __syncthreads();
    }
    // largest t with suf[t] >= TOPK (unique since suf non-increasing); 0 if none
    if (tid < NBUCK) {
        bool ge  = suf[tid] >= TOPK;
        bool nxt = (tid < NBUCK - 1) && (suf[tid + 1] >= TOPK);
        if (ge && !nxt) bstar = tid;
    }
    __syncthreads();
    const int bs = bstar;

    // phase 3: collect candidates in buckets >= bs
    for (int i = tid; i < n; i += 256) {
        unsigned long long k = cb[i];
        unsigned int vb = (unsigned int)(k >> 32);
        int bk = (int)((vb - 0x3F000000u) >> 15);
        bk = bk < 0 ? 0 : (bk > NBUCK - 1 ? NBUCK - 1 : bk);
        if (bk >= bs) {
            int s = atomicAdd(&topcount, 1);
            if (s < TOPCAP) top[s] = k;
        }
    }
    __syncthreads();
    int m = topcount; if (m > TOPCAP) m = TOPCAP;
    const int valid = n < TOPK ? n : TOPK;

    // phase 4: exact ranking among collected (keys unique — pixel idx differs)
    for (int j = tid; j < m; j += 256) {
        const unsigned long long kj = top[j];
        int rank = 0;
        for (int i = 0; i < m; ++i) rank += (top[i] > kj);
        if (rank < TOPK) {
            unsigned int vb = (unsigned int)(kj >> 32);
            int pix = (int)(~(unsigned int)kj);
            int y = pix / WW, x = pix - y * WW;
            out[COORS_OFF + ((size_t)b * TOPK + rank) * 2 + 0] = (float)y;
            out[COORS_OFF + ((size_t)b * TOPK + rank) * 2 + 1] = (float)x;
            out[SCORES_OFF + (size_t)b * TOPK + rank] = __uint_as_float(vb);
            out[MASK_OFF   + (size_t)b * TOPK + rank] = 1.0f;
            sel_pix[rank] = pix;
        }
    }
    __syncthreads();

    // phase 5: zero-fill masked tail slots (d_out is poison-filled before launch)
    for (int s = valid + tid; s < TOPK; s += 256) {
        out[COORS_OFF + ((size_t)b * TOPK + s) * 2 + 0] = 0.f;
        out[COORS_OFF + ((size_t)b * TOPK + s) * 2 + 1] = 0.f;
        out[SCORES_OFF + (size_t)b * TOPK + s] = 0.f;
        out[MASK_OFF   + (size_t)b * TOPK + s] = 0.f;
    }

    // phase 6: params gather — 100 rows x 16 float4 (256B-aligned rows)
    float4* outp = (float4*)(out + PARAMS_OFF);
    for (int l = tid; l < TOPK * (PDIM / 4); l += 256) {
        int s = l >> 4, q = l & 15;
        float4 v = make_float4(0.f, 0.f, 0.f, 0.f);
        if (s < valid) {
            int pix = sel_pix[s];
            v = ((const float4*)(pms + ((size_t)b * HW + pix) * PDIM))[q];
        }
        outp[((size_t)b * TOPK + s) * (PDIM / 4) + q] = v;
    }
}

extern "C" void kernel_launch(void* const* d_in, const int* in_sizes, int n_in,
                              void* d_out, int out_size, void* d_ws, size_t ws_size,
                              hipStream_t stream) {
    const float* hms = (const float*)d_in[0];   // [16,320,320,1] f32
    const float* pms = (const float*)d_in[1];   // [16,320,320,64] f32
    float* out = (float*)d_out;

    int* counts = (int*)d_ws;
    unsigned long long* cand = (unsigned long long*)((char*)d_ws + 256);
    int cap = (int)((ws_size - 256) / (sizeof(unsigned long long) * BATCH));
    if (cap > CAPMAX) cap = CAPMAX;

    // ws is re-poisoned (0xAA) before every timed launch: zero the counters.
    hipMemsetAsync(d_ws, 0, 256, stream);

    dim3 gridA(HW / 256, BATCH);
    peak_kernel<<<gridA, 256, 0, stream>>>(hms, cand, counts, cap);
    select_kernel<<<BATCH, 256, 0, stream>>>(cand, counts, pms, out, cap);
}

// Round 2
// 546.881 us; speedup vs baseline: 1.4065x; 1.4065x over previous
//
#include <hip/hip_runtime.h>
#include <stdint.h>

#define BATCH 16
#define HH    320
#define WW    320
#define HW    (HH * WW)          // 102400 = 400 * 256
#define PDIM  64
#define TOPK  100
#define CAPMAX 16384             // per-batch candidate capacity (expect ~5.7k)

// Output layout (all float32, concatenated in reference return order):
#define COORS_OFF   0
#define COORS_SZ    (BATCH * TOPK * 2)        // 3200
#define PARAMS_OFF  (COORS_OFF + COORS_SZ)    // 3200
#define PARAMS_SZ   (BATCH * TOPK * PDIM)     // 102400
#define SCORES_OFF  (PARAMS_OFF + PARAMS_SZ)  // 105600
#define SCORES_SZ   (BATCH * TOPK)            // 1600
#define MASK_OFF    (SCORES_OFF + SCORES_SZ)  // 107200

// ws layout: [0, 4096): int counts[16] padded 256B apart (counts[b] at int
// offset b*64) — one cache line per batch to kill atomic false sharing.
// At byte 4096: u64 cand[BATCH][cap].
#define CNT_STRIDE 64   // ints (256 B)
#define CAND_BYTE_OFF 4096

__global__ void peak_kernel(const float* __restrict__ hms,
                            unsigned long long* __restrict__ cand,
                            int* __restrict__ counts, int cap) {
    const int pix = blockIdx.x * blockDim.x + threadIdx.x;   // grid.x*256 == HW exactly
    const int b   = blockIdx.y;
    const int y = pix / WW;
    const int x = pix - y * WW;
    const float* img = hms + (size_t)b * HW;
    const float c = img[pix];
    bool peak = true;
    if (y > 0) {
        const float* r = img + pix - WW;
        if (x > 0)      peak &= (c >= r[-1]);
        peak &= (c >= r[0]);
        if (x < WW - 1) peak &= (c >= r[1]);
    }
    {
        const float* r = img + pix;
        if (x > 0)      peak &= (c >= r[-1]);
        if (x < WW - 1) peak &= (c >= r[1]);
    }
    if (y < HH - 1) {
        const float* r = img + pix + WW;
        if (x > 0)      peak &= (c >= r[-1]);
        peak &= (c >= r[0]);
        if (x < WW - 1) peak &= (c >= r[1]);
    }
    const bool pred = peak && (c > 0.5f);

    // ---- wave-aggregated slot allocation: ONE atomic per wave ----
    unsigned long long mask = __ballot(pred);
    if (mask != 0ull) {
        const int lane   = threadIdx.x & 63;
        const int leader = __ffsll((long long)mask) - 1;
        int base = 0;
        if (lane == leader)
            base = atomicAdd(&counts[b * CNT_STRIDE], __popcll(mask));
        base = __shfl(base, leader, 64);
        if (pred) {
            int off  = __popcll(mask & ((1ull << lane) - 1ull));
            int slot = base + off;
            if (slot < cap) {
                unsigned int vb = __float_as_uint(c);
                // key: value desc, pixel-index asc on tie
                cand[(size_t)b * cap + slot] =
                    ((unsigned long long)vb << 32) | (unsigned int)(~pix);
            }
        }
    }
}

#define NBUCK 256
#define TOPCAP 2048

__global__ __launch_bounds__(256)
void select_kernel(const unsigned long long* __restrict__ cand,
                   const int* __restrict__ counts,
                   const float* __restrict__ pms,
                   float* __restrict__ out, int cap) {
    __shared__ int hist[NBUCK];
    __shared__ int suf[NBUCK + 1];
    __shared__ unsigned long long top[TOPCAP];
    __shared__ int topcount;
    __shared__ int bstar;
    __shared__ int sel_pix[TOPK];

    const int b = blockIdx.x;
    const int tid = threadIdx.x;
    int n = counts[b * CNT_STRIDE];
    if (n > cap) n = cap;
    const unsigned long long* cb = cand + (size_t)b * cap;

    if (tid < NBUCK) hist[tid] = 0;
    if (tid == 0) { topcount = 0; bstar = 0; }
    __syncthreads();

    // phase 1: histogram over float-bit buckets (monotonic for positive floats)
    for (int i = tid; i < n; i += 256) {
        unsigned int vb = (unsigned int)(cb[i] >> 32);
        int bk = (int)((vb - 0x3F000000u) >> 15);   // (0.5,1.0) -> [0,255]
        bk = bk < 0 ? 0 : (bk > NBUCK - 1 ? NBUCK - 1 : bk);
        atomicAdd(&hist[bk], 1);
    }
    __syncthreads();

    // phase 2: suffix sums suf[t] = sum_{u>=t} hist[u]
    if (tid < NBUCK) suf[tid] = hist[tid];
    if (tid == 0) suf[NBUCK] = 0;
    __syncthreads();
    for (int d = 1; d < NBUCK; d <<= 1) {
        int v = 0;
        if (tid < NBUCK && tid + d < NBUCK) v = suf[tid + d];
        __syncthreads();
        if (tid < NBUCK) suf[tid] += v;
        __syncthreads();
    }
    // largest t with suf[t] >= TOPK (unique since suf non-increasing); 0 if none
    if (tid < NBUCK) {
        bool ge  = suf[tid] >= TOPK;
        bool nxt = (tid < NBUCK - 1) && (suf[tid + 1] >= TOPK);
        if (ge && !nxt) bstar = tid;
    }
    __syncthreads();
    const int bs = bstar;

    // phase 3: collect candidates in buckets >= bs
    for (int i = tid; i < n; i += 256) {
        unsigned long long k = cb[i];
        unsigned int vb = (unsigned int)(k >> 32);
        int bk = (int)((vb - 0x3F000000u) >> 15);
        bk = bk < 0 ? 0 : (bk > NBUCK - 1 ? NBUCK - 1 : bk);
        if (bk >= bs) {
            int s = atomicAdd(&topcount, 1);
            if (s < TOPCAP) top[s] = k;
        }
    }
    __syncthreads();
    int m = topcount; if (m > TOPCAP) m = TOPCAP;
    const int valid = n < TOPK ? n : TOPK;

    // phase 4: exact ranking among collected (keys unique — pixel idx differs)
    for (int j = tid; j < m; j += 256) {
        const unsigned long long kj = top[j];
        int rank = 0;
        for (int i = 0; i < m; ++i) rank += (top[i] > kj);
        if (rank < TOPK) {
            unsigned int vb = (unsigned int)(kj >> 32);
            int pix = (int)(~(unsigned int)kj);
            int y = pix / WW, x = pix - y * WW;
            out[COORS_OFF + ((size_t)b * TOPK + rank) * 2 + 0] = (float)y;
            out[COORS_OFF + ((size_t)b * TOPK + rank) * 2 + 1] = (float)x;
            out[SCORES_OFF + (size_t)b * TOPK + rank] = __uint_as_float(vb);
            out[MASK_OFF   + (size_t)b * TOPK + rank] = 1.0f;
            sel_pix[rank] = pix;
        }
    }
    __syncthreads();

    // phase 5: zero-fill masked tail slots (d_out is poison-filled before launch)
    for (int s = valid + tid; s < TOPK; s += 256) {
        out[COORS_OFF + ((size_t)b * TOPK + s) * 2 + 0] = 0.f;
        out[COORS_OFF + ((size_t)b * TOPK + s) * 2 + 1] = 0.f;
        out[SCORES_OFF + (size_t)b * TOPK + s] = 0.f;
        out[MASK_OFF   + (size_t)b * TOPK + s] = 0.f;
    }

    // phase 6: params gather — 100 rows x 16 float4 (256B-aligned rows)
    float4* outp = (float4*)(out + PARAMS_OFF);
    for (int l = tid; l < TOPK * (PDIM / 4); l += 256) {
        int s = l >> 4, q = l & 15;
        float4 v = make_float4(0.f, 0.f, 0.f, 0.f);
        if (s < valid) {
            int pix = sel_pix[s];
            v = ((const float4*)(pms + ((size_t)b * HW + pix) * PDIM))[q];
        }
        outp[((size_t)b * TOPK + s) * (PDIM / 4) + q] = v;
    }
}

extern "C" void kernel_launch(void* const* d_in, const int* in_sizes, int n_in,
                              void* d_out, int out_size, void* d_ws, size_t ws_size,
                              hipStream_t stream) {
    const float* hms = (const float*)d_in[0];   // [16,320,320,1] f32
    const float* pms = (const float*)d_in[1];   // [16,320,320,64] f32
    float* out = (float*)d_out;

    int* counts = (int*)d_ws;
    unsigned long long* cand = (unsigned long long*)((char*)d_ws + CAND_BYTE_OFF);
    int cap = (int)((ws_size - CAND_BYTE_OFF) / (sizeof(unsigned long long) * BATCH));
    if (cap > CAPMAX) cap = CAPMAX;

    // ws is re-poisoned (0xAA) before every timed launch: zero the counters.
    hipMemsetAsync(d_ws, 0, CAND_BYTE_OFF, stream);

    dim3 gridA(HW / 256, BATCH);
    peak_kernel<<<gridA, 256, 0, stream>>>(hms, cand, counts, cap);
    select_kernel<<<BATCH, 256, 0, stream>>>(cand, counts, pms, out, cap);
}

// Round 3
// 487.543 us; speedup vs baseline: 1.5777x; 1.1217x over previous
//
#include <hip/hip_runtime.h>
#include <stdint.h>

#define BATCH 16
#define HH    320
#define WW    320
#define HW    (HH * WW)          // 102400
#define PDIM  64
#define TOPK  100
#define CAPMAX 16384             // per-batch candidate capacity (expect ~5.7k)

// Output layout (all float32, concatenated in reference return order):
#define COORS_OFF   0
#define COORS_SZ    (BATCH * TOPK * 2)        // 3200
#define PARAMS_OFF  (COORS_OFF + COORS_SZ)    // 3200
#define PARAMS_SZ   (BATCH * TOPK * PDIM)     // 102400
#define SCORES_OFF  (PARAMS_OFF + PARAMS_SZ)  // 105600
#define SCORES_SZ   (BATCH * TOPK)            // 1600
#define MASK_OFF    (SCORES_OFF + SCORES_SZ)  // 107200

// ws layout: counts[b] at int offset b*64 (256B apart, no atomic line sharing);
// u64 cand[BATCH][cap] at byte 4096.
#define CNT_STRIDE 64
#define CAND_BYTE_OFF 4096

#define NEGF (-3.0e38f)

// Each thread: 4 consecutive pixels in one row (float4-aligned).
__global__ __launch_bounds__(256)
void peak_kernel(const float* __restrict__ hms,
                 unsigned long long* __restrict__ cand,
                 int* __restrict__ counts, int cap) {
    const int t    = blockIdx.x * blockDim.x + threadIdx.x;   // 0 .. HW/4-1
    const int b    = blockIdx.y;
    const int pix0 = t << 2;
    const int y    = pix0 / WW;
    const int x0   = pix0 - y * WW;                           // 0..316, step 4
    const float* row = hms + (size_t)b * HW + pix0;

    // middle row
    float4 cm = *(const float4*)row;
    float  lm = (x0 > 0)      ? row[-1] : NEGF;
    float  rm = (x0 + 4 < WW) ? row[4]  : NEGF;
    // top row
    float4 ct; float lt, rt;
    if (y > 0) {
        const float* rp = row - WW;
        ct = *(const float4*)rp;
        lt = (x0 > 0)      ? rp[-1] : NEGF;
        rt = (x0 + 4 < WW) ? rp[4]  : NEGF;
    } else { ct = make_float4(NEGF,NEGF,NEGF,NEGF); lt = NEGF; rt = NEGF; }
    // bottom row
    float4 cb; float lb, rb;
    if (y < HH - 1) {
        const float* rp = row + WW;
        cb = *(const float4*)rp;
        lb = (x0 > 0)      ? rp[-1] : NEGF;
        rb = (x0 + 4 < WW) ? rp[4]  : NEGF;
    } else { cb = make_float4(NEGF,NEGF,NEGF,NEGF); lb = NEGF; rb = NEGF; }

    float T[6] = { lt, ct.x, ct.y, ct.z, ct.w, rt };
    float M[6] = { lm, cm.x, cm.y, cm.z, cm.w, rm };
    float Bm[6] = { lb, cb.x, cb.y, cb.z, cb.w, rb };

    bool pred[4];
    float val[4];
    #pragma unroll
    for (int i = 0; i < 4; ++i) {
        float v = M[i + 1];
        float w = fmaxf(fmaxf(fmaxf(T[i], T[i+1]), fmaxf(T[i+2], M[i])),
                        fmaxf(fmaxf(M[i+2], Bm[i]), fmaxf(Bm[i+1], Bm[i+2])));
        pred[i] = (v >= w) && (v > 0.5f);
        val[i]  = v;
    }

    // ---- wave aggregation: ONE atomic per wave for all 4 sub-ballots ----
    const int lane = threadIdx.x & 63;
    unsigned long long mk[4];
    int pc[4];
    #pragma unroll
    for (int i = 0; i < 4; ++i) { mk[i] = __ballot(pred[i]); pc[i] = __popcll(mk[i]); }
    const int total = pc[0] + pc[1] + pc[2] + pc[3];
    if (total != 0) {
        int base = 0;
        if (lane == 0) base = atomicAdd(&counts[b * CNT_STRIDE], total);
        base = __shfl(base, 0, 64);
        const unsigned long long below = (lane == 63) ? ~0ull >> 1
                                                      : (1ull << lane) - 1ull;
        int pre = 0;
        #pragma unroll
        for (int i = 0; i < 4; ++i) {
            if (pred[i]) {
                int slot = base + pre + __popcll(mk[i] & below);
                if (slot < cap) {
                    unsigned int vb = __float_as_uint(val[i]);
                    int pix = pix0 + i;
                    cand[(size_t)b * cap + slot] =
                        ((unsigned long long)vb << 32) | (unsigned int)(~pix);
                }
            }
            pre += pc[i];
        }
    }
}

#define NBUCK 256
#define TOPCAP 2048

__global__ __launch_bounds__(256)
void select_kernel(const unsigned long long* __restrict__ cand,
                   const int* __restrict__ counts,
                   const float* __restrict__ pms,
                   float* __restrict__ out, int cap) {
    __shared__ int hist[NBUCK];
    __shared__ int suf[NBUCK + 1];
    __shared__ unsigned long long top[TOPCAP];
    __shared__ int topcount;
    __shared__ int bstar;
    __shared__ int sel_pix[TOPK];

    const int b = blockIdx.x;
    const int tid = threadIdx.x;
    int n = counts[b * CNT_STRIDE];
    if (n > cap) n = cap;
    const unsigned long long* cb = cand + (size_t)b * cap;

    if (tid < NBUCK) hist[tid] = 0;
    if (tid == 0) { topcount = 0; bstar = 0; }
    __syncthreads();

    // phase 1: histogram over float-bit buckets (monotonic for positive floats)
    for (int i = tid; i < n; i += 256) {
        unsigned int vb = (unsigned int)(cb[i] >> 32);
        int bk = (int)((vb - 0x3F000000u) >> 15);   // (0.5,1.0) -> [0,255]
        bk = bk < 0 ? 0 : (bk > NBUCK - 1 ? NBUCK - 1 : bk);
        atomicAdd(&hist[bk], 1);
    }
    __syncthreads();

    // phase 2: suffix sums suf[t] = sum_{u>=t} hist[u]
    if (tid < NBUCK) suf[tid] = hist[tid];
    if (tid == 0) suf[NBUCK] = 0;
    __syncthreads();
    for (int d = 1; d < NBUCK; d <<= 1) {
        int v = 0;
        if (tid < NBUCK && tid + d < NBUCK) v = suf[tid + d];
        __syncthreads();
        if (tid < NBUCK) suf[tid] += v;
        __syncthreads();
    }
    if (tid < NBUCK) {
        bool ge  = suf[tid] >= TOPK;
        bool nxt = (tid < NBUCK - 1) && (suf[tid + 1] >= TOPK);
        if (ge && !nxt) bstar = tid;
    }
    __syncthreads();
    const int bs = bstar;

    // phase 3: collect candidates in buckets >= bs
    for (int i = tid; i < n; i += 256) {
        unsigned long long k = cb[i];
        unsigned int vb = (unsigned int)(k >> 32);
        int bk = (int)((vb - 0x3F000000u) >> 15);
        bk = bk < 0 ? 0 : (bk > NBUCK - 1 ? NBUCK - 1 : bk);
        if (bk >= bs) {
            int s = atomicAdd(&topcount, 1);
            if (s < TOPCAP) top[s] = k;
        }
    }
    __syncthreads();
    int m = topcount; if (m > TOPCAP) m = TOPCAP;
    const int valid = n < TOPK ? n : TOPK;

    // phase 4: exact ranking among collected (keys unique — pixel idx differs)
    for (int j = tid; j < m; j += 256) {
        const unsigned long long kj = top[j];
        int rank = 0;
        for (int i = 0; i < m; ++i) rank += (top[i] > kj);
        if (rank < TOPK) {
            unsigned int vb = (unsigned int)(kj >> 32);
            int pix = (int)(~(unsigned int)kj);
            int y = pix / WW, x = pix - y * WW;
            out[COORS_OFF + ((size_t)b * TOPK + rank) * 2 + 0] = (float)y;
            out[COORS_OFF + ((size_t)b * TOPK + rank) * 2 + 1] = (float)x;
            out[SCORES_OFF + (size_t)b * TOPK + rank] = __uint_as_float(vb);
            out[MASK_OFF   + (size_t)b * TOPK + rank] = 1.0f;
            sel_pix[rank] = pix;
        }
    }
    __syncthreads();

    // phase 5: zero-fill masked tail slots (d_out is poison-filled before launch)
    for (int s = valid + tid; s < TOPK; s += 256) {
        out[COORS_OFF + ((size_t)b * TOPK + s) * 2 + 0] = 0.f;
        out[COORS_OFF + ((size_t)b * TOPK + s) * 2 + 1] = 0.f;
        out[SCORES_OFF + (size_t)b * TOPK + s] = 0.f;
        out[MASK_OFF   + (size_t)b * TOPK + s] = 0.f;
    }

    // phase 6: params gather — 100 rows x 16 float4 (256B rows)
    float4* outp = (float4*)(out + PARAMS_OFF);
    for (int l = tid; l < TOPK * (PDIM / 4); l += 256) {
        int s = l >> 4, q = l & 15;
        float4 v = make_float4(0.f, 0.f, 0.f, 0.f);
        if (s < valid) {
            int pix = sel_pix[s];
            v = ((const float4*)(pms + ((size_t)b * HW + pix) * PDIM))[q];
        }
        outp[((size_t)b * TOPK + s) * (PDIM / 4) + q] = v;
    }
}

extern "C" void kernel_launch(void* const* d_in, const int* in_sizes, int n_in,
                              void* d_out, int out_size, void* d_ws, size_t ws_size,
                              hipStream_t stream) {
    const float* hms = (const float*)d_in[0];   // [16,320,320,1] f32
    const float* pms = (const float*)d_in[1];   // [16,320,320,64] f32
    float* out = (float*)d_out;

    int* counts = (int*)d_ws;
    unsigned long long* cand = (unsigned long long*)((char*)d_ws + CAND_BYTE_OFF);
    int cap = (int)((ws_size - CAND_BYTE_OFF) / (sizeof(unsigned long long) * BATCH));
    if (cap > CAPMAX) cap = CAPMAX;

    // ws is re-poisoned (0xAA) before every timed launch: zero the counters.
    hipMemsetAsync(d_ws, 0, CAND_BYTE_OFF, stream);

    dim3 gridA(HW / (4 * 256), BATCH);   // 100 x 16 blocks
    peak_kernel<<<gridA, 256, 0, stream>>>(hms, cand, counts, cap);
    select_kernel<<<BATCH, 256, 0, stream>>>(cand, counts, pms, out, cap);
}